// Round 18
// baseline (26.745 us; speedup 1.0000x reference)
//
#include <hip/hip_runtime.h>
#include <hip/hip_bf16.h>

#define BS 512
#define MARGIN 0.5f
#define NBLK 512

using short8 = __attribute__((ext_vector_type(8))) short;
using f32x4 = __attribute__((ext_vector_type(4))) float;

__device__ inline short bf16_rne(float x) {
    __hip_bfloat16 h = __float2bfloat16(x);
    return *(short*)&h;
}

// Kernel 1: compacted-dist, 16x32 tiles (1 wave per block, 512 blocks -> all
// 256 CUs active at npos=256). Row space = pos-rank (MARGIN-folded pos cols
// first, then neg cols). Per-block ballot compaction; block (0,0) publishes
// counts and zeroes fin BEFORE its early-exit check.
__global__ __launch_bounds__(64) void kdistf(const float* __restrict__ pred,
                                             const int* __restrict__ target,
                                             float* __restrict__ dist,
                                             int* __restrict__ counts,
                                             unsigned int* __restrict__ fin) {
    const int lane = threadIdx.x;
    __shared__ int plist[BS];
    __shared__ int rnk[BS];
    __shared__ int tgs[BS];

    // one-wave stable compaction: pos-rank / neg-rank per index
    int pbase = 0, nbase = 0;
    const unsigned long long below = (1ULL << lane) - 1ULL;
#pragma unroll
    for (int c = 0; c < 8; ++c) {
        const int idx = c * 64 + lane;
        const int tg = target[idx];
        const unsigned long long mp = __ballot(tg == 1);
        const int prk = pbase + __popcll(mp & below);
        const int nrk = nbase + __popcll((~mp) & below);
        tgs[idx] = tg;
        rnk[idx] = (tg == 1) ? prk : nrk;
        if (tg == 1) plist[prk] = idx;
        const int np = __popcll(mp);
        pbase += np;
        nbase += 64 - np;
    }
    const int npos = pbase;
    __syncthreads();

    if (blockIdx.x == 0 && blockIdx.y == 0 && lane == 0) {
        counts[0] = npos;
        counts[1] = nbase;
        *fin = 0u;
    }

    const int r0 = blockIdx.y * 16;  // pos-space row tile (16 rows)
    if (r0 >= npos) return;
    const int c0 = blockIdx.x * 32;  // col tile (32 cols)
    const int rl = lane & 15;
    const int koff = (lane >> 4) * 8;

    const int pr = min(r0 + rl, npos - 1);
    const float* A = pred + plist[pr] * BS;
    const float* B0 = pred + (c0 + rl) * BS;
    const float* B1 = pred + (c0 + 16 + rl) * BS;

    f32x4 acc0 = {0.f, 0.f, 0.f, 0.f};
    f32x4 acc1 = {0.f, 0.f, 0.f, 0.f};
    float na = 0.f, nb0 = 0.f, nb1 = 0.f;

#pragma unroll 4
    for (int ks = 0; ks < 16; ++ks) {
        const int k = ks * 32 + koff;
        const f32x4 al = *(const f32x4*)(A + k);
        const f32x4 ah = *(const f32x4*)(A + k + 4);
        const f32x4 b0l = *(const f32x4*)(B0 + k);
        const f32x4 b0h = *(const f32x4*)(B0 + k + 4);
        const f32x4 b1l = *(const f32x4*)(B1 + k);
        const f32x4 b1h = *(const f32x4*)(B1 + k + 4);

        short8 sa, sb0, sb1;
#pragma unroll
        for (int j = 0; j < 4; ++j) {
            na += al[j] * al[j] + ah[j] * ah[j];
            nb0 += b0l[j] * b0l[j] + b0h[j] * b0h[j];
            nb1 += b1l[j] * b1l[j] + b1h[j] * b1h[j];
            sa[j] = bf16_rne(al[j]);  sa[4 + j] = bf16_rne(ah[j]);
            sb0[j] = bf16_rne(b0l[j]); sb0[4 + j] = bf16_rne(b0h[j]);
            sb1[j] = bf16_rne(b1l[j]); sb1[4 + j] = bf16_rne(b1h[j]);
        }
        acc0 = __builtin_amdgcn_mfma_f32_16x16x32_bf16(sa, sb0, acc0, 0, 0, 0);
        acc1 = __builtin_amdgcn_mfma_f32_16x16x32_bf16(sa, sb1, acc1, 0, 0, 0);
    }

    na += __shfl_xor(na, 16, 64); na += __shfl_xor(na, 32, 64);
    nb0 += __shfl_xor(nb0, 16, 64); nb0 += __shfl_xor(nb0, 32, 64);
    nb1 += __shfl_xor(nb1, 16, 64); nb1 += __shfl_xor(nb1, 32, 64);
    const float ia = 1.0f / fmaxf(sqrtf(na), 1e-10f);
    const float ib0 = 1.0f / fmaxf(sqrtf(nb0), 1e-10f);
    const float ib1 = 1.0f / fmaxf(sqrtf(nb1), 1e-10f);

    // C/D layout: col = lane&15 (B row), row = (lane>>4)*4 + reg (A row)  [m89]
    const int rbase = (lane >> 4) * 4;
#pragma unroll
    for (int fc = 0; fc < 2; ++fc) {
        const f32x4 v = (fc == 0) ? acc0 : acc1;
        const int col = c0 + fc * 16 + rl;
        const float icol = (fc == 0) ? ib0 : ib1;
        const int isPos = tgs[col];
        const int ccol = (isPos == 1) ? rnk[col] : npos + rnk[col];
        const float addM = (isPos == 1) ? MARGIN : 0.0f;
#pragma unroll
        for (int r = 0; r < 4; ++r) {
            const float irow = __shfl(ia, rbase + r, 64);
            const int rowp = r0 + rbase + r;  // pos-rank row
            if (rowp < npos) {
                float d2 = 2.0f - 2.0f * v[r] * irow * icol;
                dist[rowp * BS + ccol] = sqrtf(fmaxf(d2, 0.f)) + addM;
            }
        }
    }
}

// Kernel 2: block b = pos-rank anchor. Coalesced loads from compacted dist.
// Done-counter tail (measured free in R7/R8): last block reduces 512 slots.
__global__ __launch_bounds__(256) void ktriplet(const float* __restrict__ dist,
                                                const int* __restrict__ counts,
                                                float* __restrict__ psum,
                                                float* __restrict__ pcnt,
                                                unsigned int* __restrict__ fin,
                                                float* __restrict__ out) {
    const int b = blockIdx.x;
    const int tid = threadIdx.x;
    const int lane = tid & 63;
    const int w = tid >> 6;
    const int npos = counts[0];
    const int nneg = counts[1];
    __shared__ float sbuf[4];
    __shared__ float cbuf[4];
    __shared__ unsigned int slast;

    float sum = 0.f;
    unsigned int cw = 0;

    if (b < npos) {  // block-uniform
        const float* drow = dist + b * BS;

        // k-role: coalesced from [npos + tid]
        const float bv0 = (tid < nneg) ? drow[npos + tid] : 1e30f;
        const float bv1 = (tid + 256 < nneg) ? drow[npos + 256 + tid] : 1e30f;

        // j-role: wave w owns chunks w and w+4; margin already folded
        const int ja = w * 64 + lane;
        const int jb = (w + 4) * 64 + lane;
        const float av0 = (ja < npos && ja != b) ? drow[ja] : -1e9f;
        const float av1 = (jb < npos && jb != b) ? drow[jb] : -1e9f;

#define HINGE(TJ, BK)                                       \
    do {                                                    \
        const float v_ = (TJ) - (BK);                       \
        sum += fmaxf(v_, 0.f);                              \
        cw += (unsigned int)__popcll(__ballot(v_ > 0.f));   \
    } while (0)

        if (nneg > 256) {  // uniform rare path
            if (w * 64 < npos) {
#pragma unroll 8
                for (int jj = 0; jj < 64; ++jj) {
                    const float tj = __int_as_float(
                        __builtin_amdgcn_readlane(__float_as_int(av0), jj));
                    HINGE(tj, bv0); HINGE(tj, bv1);
                }
            }
            if ((w + 4) * 64 < npos) {
#pragma unroll 8
                for (int jj = 0; jj < 64; ++jj) {
                    const float tj = __int_as_float(
                        __builtin_amdgcn_readlane(__float_as_int(av1), jj));
                    HINGE(tj, bv0); HINGE(tj, bv1);
                }
            }
        } else {  // typical: nneg <= 256
            if (w * 64 < npos) {
#pragma unroll 8
                for (int jj = 0; jj < 64; ++jj) {
                    const float tj = __int_as_float(
                        __builtin_amdgcn_readlane(__float_as_int(av0), jj));
                    HINGE(tj, bv0);
                }
            }
            if ((w + 4) * 64 < npos) {
#pragma unroll 8
                for (int jj = 0; jj < 64; ++jj) {
                    const float tj = __int_as_float(
                        __builtin_amdgcn_readlane(__float_as_int(av1), jj));
                    HINGE(tj, bv0);
                }
            }
        }
#undef HINGE
    }

    float wsm = sum;
#pragma unroll
    for (int o = 32; o > 0; o >>= 1) wsm += __shfl_xor(wsm, o, 64);
    if (lane == 0) { sbuf[w] = wsm; cbuf[w] = (float)cw; }
    __syncthreads();
    if (tid == 0) {
        psum[b] = (sbuf[0] + sbuf[1]) + (sbuf[2] + sbuf[3]);
        pcnt[b] = (cbuf[0] + cbuf[1]) + (cbuf[2] + cbuf[3]);
        __threadfence();  // release partials
        slast = (atomicAdd(fin, 1u) == (unsigned int)(NBLK - 1)) ? 1u : 0u;
    }
    __syncthreads();
    if (slast != 0 && tid < 64) {
        __threadfence();  // acquire
        float s = 0.f, c = 0.f;
#pragma unroll
        for (int r = 0; r < 8; ++r) {
            s += psum[r * 64 + tid];
            c += pcnt[r * 64 + tid];
        }
#pragma unroll
        for (int o = 32; o > 0; o >>= 1) {
            s += __shfl_xor(s, o, 64);
            c += __shfl_xor(c, o, 64);
        }
        if (tid == 0) out[0] = s / (c + 1e-7f);
    }
}

extern "C" void kernel_launch(void* const* d_in, const int* in_sizes, int n_in,
                              void* d_out, int out_size, void* d_ws, size_t ws_size,
                              hipStream_t stream) {
    const float* pred = (const float*)d_in[0];
    const int* target = (const int*)d_in[1];
    float* out = (float*)d_out;
    char* base = (char*)d_ws;

    float* dist = (float*)base;                     // 1 MB (compacted both axes)
    float* psum = (float*)(base + 1048576);         // 2 KB
    float* pcnt = (float*)(base + 1050624);         // 2 KB
    int* counts = (int*)(base + 1052672);           // 8 B
    unsigned int* fin = (unsigned int*)(base + 1052736);

    dim3 gb(16, 32);  // x: 16 col-tiles (32 cols), y: 32 row-tiles (16 pos rows)
    kdistf<<<gb, 64, 0, stream>>>(pred, target, dist, counts, fin);
    ktriplet<<<NBLK, 256, 0, stream>>>(dist, counts, psum, pcnt, fin, out);
}